// Round 8
// baseline (37.445 us; speedup 1.0000x reference)
//
#include <hip/hip_runtime.h>

// ConvNeXtLoss: fused attention-BCE + dice + reverse-dice over (16,4,512,512).
// Pass 1: per-chunk partial sums via global_load_lds staging.
// Pass 2: tiny 64-lane finalize kernel. No fences/atomics (R5/R6 lesson:
// per-block __threadfence = device L2 writeback x nblocks = 10x regression).
//
// R8 changes vs R7 (30.5 us): R7's serial [stage -> barrier -> compute]
// with only 2 lockstep blocks/CU leaves the memory queues EMPTY during
// every compute phase (~40% of time). Fix = phase diversity: 128-thread
// blocks with 16 KB LDS -> ~9 resident blocks/CU at independent phases,
// so some blocks always have DMA in flight while others compute. Per-wave
// DMA depth unchanged (8 x 1 KB global_load_lds, 16B/lane).

typedef float f32x4 __attribute__((ext_vector_type(4)));
typedef int   i32x4 __attribute__((ext_vector_type(4)));

#define B_DIM 16
#define C_DIM 4
#define HW 262144                 // 512*512 plane
#define NPLANES 64                // B*C
#define NTHREADS 128
#define NWAVES (NTHREADS / 64)    // 2
#define CHUNK 2048                // elements per block
#define K_CHUNKS (HW / CHUNK)     // 128 chunks per plane
#define NBLOCKS (NPLANES * K_CHUNKS)  // 8192
#define NSUMS 6
#define WELEMS (CHUNK / NWAVES)   // 1024 elems per wave
#define WOPS (WELEMS / 256)       // 4 DMA rounds per array per wave

__global__ __launch_bounds__(NTHREADS) void loss_main(
    const float* __restrict__ pred, const int* __restrict__ label,
    float* __restrict__ ws) {
  __shared__ float sp[NWAVES][WELEMS];   // 8 KB
  __shared__ int   st[NWAVES][WELEMS];   // 8 KB
  __shared__ float red[NWAVES][NSUMS];

  const int block = blockIdx.x;          // 0..8191
  const int tid = threadIdx.x;
  const int w = tid >> 6, l = tid & 63;
  const long wbase = (long)block * CHUNK + (long)w * WELEMS;
  const float* gp = pred + wbase;
  const int*   gt = label + wbase;

  // ---- stage the wave's whole chunk: 8 async DMA ops (8 KB in flight) ----
  // LDS dest is wave-uniform base (+lane*16 by HW); global src per-lane.
#pragma unroll
  for (int r = 0; r < WOPS; ++r) {
    __builtin_amdgcn_global_load_lds(
        (const __attribute__((address_space(1))) void*)(gp + r * 256 + l * 4),
        (__attribute__((address_space(3))) void*)(&sp[w][r * 256]), 16, 0, 0);
    __builtin_amdgcn_global_load_lds(
        (const __attribute__((address_space(1))) void*)(gt + r * 256 + l * 4),
        (__attribute__((address_space(3))) void*)(&st[w][r * 256]), 16, 0, 0);
  }
  __syncthreads();   // vmcnt(0) drain; other resident blocks cover the gap

  float s_pt = 0.f, s_pp = 0.f, s_p = 0.f;
  float nsum_t = 0.f;   // sum over ALL elems of Bw * (-L)
  float nsum_1 = 0.f;   // sum over t==1 elems of Bw * (-L)
  int   s_ti = 0;       // integer count of positives

#pragma unroll
  for (int r = 0; r < WOPS; ++r) {
    f32x4 P = *(const f32x4*)&sp[w][r * 256 + l * 4];
    i32x4 T = *(const i32x4*)&st[w][r * 256 + l * 4];
#pragma unroll
    for (int j = 0; j < 4; ++j) {
      float pv = P[j];
      float tf = (float)T[j];                        // labels exactly 0/1
      float u   = __builtin_fmaf(tf, -2.0f, 1.0f);   // 1-2t
      float arg = __builtin_fmaf(pv, u, tf);         // t ? p : 1-p
      float x   = 1.0f - arg;                        // t ? 1-p : p
      float r_  = __builtin_amdgcn_sqrtf(x);
      float Bw  = __builtin_amdgcn_exp2f(3.0f * r_); // 8^sqrt(x)
      float lg  = __builtin_amdgcn_logf(arg);        // log2
      float L   = fmaxf(0.69314718056f * lg, -100.0f);
      float c   = Bw * (-L);
      nsum_t += c;
      nsum_1  = __builtin_fmaf(tf, c, nsum_1);
      s_pt    = __builtin_fmaf(tf, pv, s_pt);
      s_pp    = __builtin_fmaf(pv, pv, s_pp);
      s_p    += pv;
      s_ti   += T[j];
    }
  }

  float s_t = (float)s_ti;

  // wave reduce (64 lanes), then cross-wave via LDS
  float vals[NSUMS] = {s_pt, s_pp, s_t, s_p, nsum_1, nsum_t};
#pragma unroll
  for (int q = 0; q < NSUMS; ++q) {
    float v = vals[q];
#pragma unroll
    for (int off = 32; off; off >>= 1) v += __shfl_down(v, off);
    vals[q] = v;
  }
  if (l == 0) {
#pragma unroll
    for (int q = 0; q < NSUMS; ++q) red[w][q] = vals[q];
  }
  __syncthreads();
  if (tid < NSUMS) {
    float v = 0.f;
#pragma unroll
    for (int ww = 0; ww < NWAVES; ++ww) v += red[ww][tid];
    ws[block * NSUMS + tid] = v;
  }
}

__global__ __launch_bounds__(64) void loss_finalize(
    const float* __restrict__ ws, float* __restrict__ out) {
  const int p = threadIdx.x;  // plane index 0..63 ; b = p>>2, c = p&3
  float s[NSUMS] = {0.f, 0.f, 0.f, 0.f, 0.f, 0.f};
  for (int k = 0; k < K_CHUNKS; ++k) {
    const float* w = ws + ((long)p * K_CHUNKS + k) * NSUMS;
#pragma unroll
    for (int q = 0; q < NSUMS; ++q) s[q] += w[q];
  }
  const float s_pt = s[0], s_pp = s[1], s_t = s[2], s_p = s[3];
  const float sum1 = s[4];             // t==1 part
  const float sum2 = s[5] - s[4];      // t==0 part
  const float N = (float)HW;
  const float SM = 1e-6f;

  // dice (per plane): 1 - (2*inter + S)/(sum p^2 + sum t + S)   [t^2 = t]
  float dice = 1.0f - (2.0f * s_pt + SM) / (s_pp + s_t + SM);
  // reverse dice via algebraic identities
  float inter2 = N - s_p - s_t + s_pt;
  float denom2 = 2.0f * N - 2.0f * s_p + s_pp - s_t;
  float rdice = 1.0f - (2.0f * inter2 + SM) / (denom2 + SM);

  // per-batch num_pos: sum s_t over the 4 channel lanes (p groups of 4)
  float np4 = s_t + __shfl_xor(s_t, 1);
  np4 += __shfl_xor(np4, 2);
  const float total = (float)(C_DIM * HW);  // 1048576
  float alpha = (total - np4) / total;

  float val = alpha * sum1 + (1.0f - alpha) * sum2
            + 2500.0f * (dice + rdice);   // DICE_COEFF == REV_DICE_COEFF

#pragma unroll
  for (int off = 32; off; off >>= 1) val += __shfl_down(val, off);
  if (p == 0) out[0] = val;
}

extern "C" void kernel_launch(void* const* d_in, const int* in_sizes, int n_in,
                              void* d_out, int out_size, void* d_ws, size_t ws_size,
                              hipStream_t stream) {
  const float* pred = (const float*)d_in[0];
  const int* label = (const int*)d_in[1];
  float* out = (float*)d_out;
  float* ws = (float*)d_ws;  // needs NBLOCKS*NSUMS*4 = 192 KiB

  loss_main<<<NBLOCKS, NTHREADS, 0, stream>>>(pred, label, ws);
  loss_finalize<<<1, 64, 0, stream>>>(ws, out);
}

// Round 9
// 31.179 us; speedup vs baseline: 1.2009x; 1.2009x over previous
//
#include <hip/hip_runtime.h>

// ConvNeXtLoss: fused attention-BCE + dice + reverse-dice over (16,4,512,512).
// Pass 1: per-chunk partial sums via global_load_lds staging (R8 main,
//         unchanged: 128-thread blocks, 16KB LDS, ~9 blocks/CU phase
//         diversity keeps DMA queues fed through barrier drains).
// Pass 2: PARALLEL finalize (R9 fix): R8's 64-lane finalize did 128 serial
//         latency-bound iterations (~12-16 us tail!). Now 1024 threads:
//         16 threads/plane read 12x float4 each (compile-time q pattern),
//         shfl_xor group-reduce, plane sums via LDS, then the original
//         64-lane epilogue math. ~1-2 us.
// No fences/atomics (R5/R6 lesson: per-block __threadfence = 10x regression).

typedef float f32x4 __attribute__((ext_vector_type(4)));
typedef int   i32x4 __attribute__((ext_vector_type(4)));

#define B_DIM 16
#define C_DIM 4
#define HW 262144                 // 512*512 plane
#define NPLANES 64                // B*C
#define NTHREADS 128
#define NWAVES (NTHREADS / 64)    // 2
#define CHUNK 2048                // elements per block
#define K_CHUNKS (HW / CHUNK)     // 128 chunks per plane
#define NBLOCKS (NPLANES * K_CHUNKS)  // 8192
#define NSUMS 6
#define WELEMS (CHUNK / NWAVES)   // 1024 elems per wave
#define WOPS (WELEMS / 256)       // 4 DMA rounds per array per wave

__global__ __launch_bounds__(NTHREADS) void loss_main(
    const float* __restrict__ pred, const int* __restrict__ label,
    float* __restrict__ ws) {
  __shared__ float sp[NWAVES][WELEMS];   // 8 KB
  __shared__ int   st[NWAVES][WELEMS];   // 8 KB
  __shared__ float red[NWAVES][NSUMS];

  const int block = blockIdx.x;          // 0..8191
  const int tid = threadIdx.x;
  const int w = tid >> 6, l = tid & 63;
  const long wbase = (long)block * CHUNK + (long)w * WELEMS;
  const float* gp = pred + wbase;
  const int*   gt = label + wbase;

  // ---- stage the wave's whole chunk: 8 async DMA ops (8 KB in flight) ----
#pragma unroll
  for (int r = 0; r < WOPS; ++r) {
    __builtin_amdgcn_global_load_lds(
        (const __attribute__((address_space(1))) void*)(gp + r * 256 + l * 4),
        (__attribute__((address_space(3))) void*)(&sp[w][r * 256]), 16, 0, 0);
    __builtin_amdgcn_global_load_lds(
        (const __attribute__((address_space(1))) void*)(gt + r * 256 + l * 4),
        (__attribute__((address_space(3))) void*)(&st[w][r * 256]), 16, 0, 0);
  }
  __syncthreads();   // vmcnt(0) drain; other resident blocks cover the gap

  float s_pt = 0.f, s_pp = 0.f, s_p = 0.f;
  float nsum_t = 0.f;   // sum over ALL elems of Bw * (-L)
  float nsum_1 = 0.f;   // sum over t==1 elems of Bw * (-L)
  int   s_ti = 0;       // integer count of positives

#pragma unroll
  for (int r = 0; r < WOPS; ++r) {
    f32x4 P = *(const f32x4*)&sp[w][r * 256 + l * 4];
    i32x4 T = *(const i32x4*)&st[w][r * 256 + l * 4];
#pragma unroll
    for (int j = 0; j < 4; ++j) {
      float pv = P[j];
      float tf = (float)T[j];                        // labels exactly 0/1
      float u   = __builtin_fmaf(tf, -2.0f, 1.0f);   // 1-2t
      float arg = __builtin_fmaf(pv, u, tf);         // t ? p : 1-p
      float x   = 1.0f - arg;                        // t ? 1-p : p
      float r_  = __builtin_amdgcn_sqrtf(x);
      float Bw  = __builtin_amdgcn_exp2f(3.0f * r_); // 8^sqrt(x)
      float lg  = __builtin_amdgcn_logf(arg);        // log2
      float L   = fmaxf(0.69314718056f * lg, -100.0f);
      float c   = Bw * (-L);
      nsum_t += c;
      nsum_1  = __builtin_fmaf(tf, c, nsum_1);
      s_pt    = __builtin_fmaf(tf, pv, s_pt);
      s_pp    = __builtin_fmaf(pv, pv, s_pp);
      s_p    += pv;
      s_ti   += T[j];
    }
  }

  float s_t = (float)s_ti;

  // wave reduce (64 lanes), then cross-wave via LDS
  float vals[NSUMS] = {s_pt, s_pp, s_t, s_p, nsum_1, nsum_t};
#pragma unroll
  for (int q = 0; q < NSUMS; ++q) {
    float v = vals[q];
#pragma unroll
    for (int off = 32; off; off >>= 1) v += __shfl_down(v, off);
    vals[q] = v;
  }
  if (l == 0) {
#pragma unroll
    for (int q = 0; q < NSUMS; ++q) red[w][q] = vals[q];
  }
  __syncthreads();
  if (tid < NSUMS) {
    float v = 0.f;
#pragma unroll
    for (int ww = 0; ww < NWAVES; ++ww) v += red[ww][tid];
    ws[block * NSUMS + tid] = v;
  }
}

// Parallel finalize: 1 block x 1024 threads. 16 threads per plane; each
// reads 48 consecutive floats (12 x float4) of the plane's 768-float
// partial strip; q = position % 6 is compile-time (pattern period 3 loads).
__global__ __launch_bounds__(1024) void loss_finalize(
    const float* __restrict__ ws, float* __restrict__ out) {
  __shared__ float ps[NPLANES][NSUMS];
  const int tid = threadIdx.x;
  const int p = tid >> 4;       // plane 0..63
  const int s = tid & 15;       // sub-slice 0..15

  float acc[NSUMS] = {0.f, 0.f, 0.f, 0.f, 0.f, 0.f};
  const f32x4* base =
      (const f32x4*)(ws + (long)p * (K_CHUNKS * NSUMS) + s * 48);
#pragma unroll
  for (int i = 0; i < 12; ++i) {
    f32x4 v = base[i];
#pragma unroll
    for (int j = 0; j < 4; ++j) acc[(i * 4 + j) % 6] += v[j];
  }
  // reduce the 16-lane plane group (xor masks stay within the group)
#pragma unroll
  for (int q = 0; q < NSUMS; ++q) {
    float v = acc[q];
    v += __shfl_xor(v, 1);
    v += __shfl_xor(v, 2);
    v += __shfl_xor(v, 4);
    v += __shfl_xor(v, 8);
    acc[q] = v;
  }
  if (s == 0) {
#pragma unroll
    for (int q = 0; q < NSUMS; ++q) ps[p][q] = acc[q];
  }
  __syncthreads();

  if (tid < 64) {
    const int pl = tid;        // plane index; b = pl>>2, c = pl&3
    const float s_pt = ps[pl][0], s_pp = ps[pl][1], s_t = ps[pl][2],
                s_p = ps[pl][3];
    const float sum1 = ps[pl][4];            // t==1 part
    const float sum2 = ps[pl][5] - ps[pl][4];// t==0 part
    const float N = (float)HW;
    const float SM = 1e-6f;

    float dice = 1.0f - (2.0f * s_pt + SM) / (s_pp + s_t + SM);
    float inter2 = N - s_p - s_t + s_pt;
    float denom2 = 2.0f * N - 2.0f * s_p + s_pp - s_t;
    float rdice = 1.0f - (2.0f * inter2 + SM) / (denom2 + SM);

    // per-batch num_pos: planes 4b..4b+3 are lanes 4b..4b+3 of wave 0
    float np4 = s_t + __shfl_xor(s_t, 1);
    np4 += __shfl_xor(np4, 2);
    const float total = (float)(C_DIM * HW);  // 1048576
    float alpha = (total - np4) / total;

    float val = alpha * sum1 + (1.0f - alpha) * sum2
              + 2500.0f * (dice + rdice);   // DICE_COEFF == REV_DICE_COEFF

#pragma unroll
    for (int off = 32; off; off >>= 1) val += __shfl_down(val, off);
    if (pl == 0) out[0] = val;
  }
}

extern "C" void kernel_launch(void* const* d_in, const int* in_sizes, int n_in,
                              void* d_out, int out_size, void* d_ws, size_t ws_size,
                              hipStream_t stream) {
  const float* pred = (const float*)d_in[0];
  const int* label = (const int*)d_in[1];
  float* out = (float*)d_out;
  float* ws = (float*)d_ws;  // needs NBLOCKS*NSUMS*4 = 192 KiB

  loss_main<<<NBLOCKS, NTHREADS, 0, stream>>>(pred, label, ws);
  loss_finalize<<<1, 1024, 0, stream>>>(ws, out);
}